// Round 9
// baseline (108.468 us; speedup 1.0000x reference)
//
#include <hip/hip_runtime.h>

typedef _Float16 f16x8 __attribute__((ext_vector_type(8)));
typedef _Float16 f16x4 __attribute__((ext_vector_type(4)));
typedef float    f32x4 __attribute__((ext_vector_type(4)));

// ---------------- workspace layout (bytes) ----------------
#define WAP_OFF   33554432u   // fragment-packed Wa fp16 (393216 B)
#define WVP_OFF   33947648u
#define CORRT_OFF 34340864u
#define WBT_OFF   34471936u

// =========================================================
// k_prep: (blocks 0..191) Wa/Wv [768,256] fp32 -> MFMA-fragment-
//  packed fp16: frag (kc,nb) = 64 lanes x 16B, lane l=(q,lm) holds
//  W[kc*32+q*8+e][nb*16+lm]. (192..215) corr->corrT, Wb->WbT.
// =========================================================
__global__ __launch_bounds__(256) void k_prep(
    const float* __restrict__ Wa, const float* __restrict__ Wv,
    const float* __restrict__ corr, const float* __restrict__ Wb,
    _Float16* __restrict__ WaP, _Float16* __restrict__ WvP,
    _Float16* __restrict__ corrT, _Float16* __restrict__ WbT)
{
    __shared__ _Float16 tile[64][72];
    int bid = blockIdx.x;
    int t = threadIdx.x;
    if (bid < 192) {
        int z = bid >= 96;
        int b = z ? bid - 96 : bid;
        const float* W = z ? Wv : Wa;
        _Float16* P = z ? WvP : WaP;
        int kc = b >> 2, nbg = b & 3;
        int l = t & 63, sub = t >> 6;
        int nb = nbg * 4 + sub;
        int q = l >> 4, lm = l & 15;
        int k0 = kc * 32 + q * 8;
        int n = nb * 16 + lm;
        _Float16 tmp[8];
        #pragma unroll
        for (int e = 0; e < 8; ++e)
            tmp[e] = (_Float16)W[(size_t)(k0 + e) * 256 + n];
        *reinterpret_cast<f16x8*>(P + ((size_t)(kc * 16 + nb) * 64 + l) * 8) =
            *reinterpret_cast<const f16x8*>(tmp);
    } else {
        int b2 = bid - 192;
        const float* src; _Float16* dst; int R, C, tr, tc;
        if (b2 < 16) { src = corr; dst = corrT; R = 256; C = 256; tr = b2 >> 2; tc = b2 & 3; }
        else         { src = Wb;   dst = WbT;   R = 512; C = 64;  tr = b2 - 16; tc = 0;      }
        int r0 = tr * 64, c0 = tc * 64;
        #pragma unroll
        for (int it = 0; it < 16; ++it) {
            int idx = t + it * 256;
            int r = idx >> 6, c = idx & 63;
            tile[r][c] = (_Float16)src[(size_t)(r0 + r) * C + (c0 + c)];
        }
        __syncthreads();
        #pragma unroll
        for (int it = 0; it < 16; ++it) {
            int idx = t + it * 256;
            int c = idx >> 6, r = idx & 63;
            dst[(size_t)(c0 + c) * R + (r0 + r)] = tile[r][c];
        }
    }
}

// =========================================================
// kF: fully fused per-batch kernel. 512 blocks x 512 thr, 160 KiB LDS.
//  LDS map (dynamic 163840 B):
//   [0,98304)      Xs fp16 [64][768] row-XOR-swizzled (staging)
//     overlay after GEMMs:
//       AC 0..32768 (swz [64][256] f16), CC 32768..49664 (f32 [64][66]),
//       ATA 49664, ATV 58880, AWT 68096, VWT 77312 (each f16 [64][72]),
//       RED 86528..90624 (f32 [4][256])
//   [98304,131072)  a_s swz [64][256] f16
//   [131072,163840) v_s swz [64][256] f16
//  Pipeline: stage(a,h0); [gemm ∥ stage-next] x4; phases B..G.
// =========================================================
#define XS_OFF  0
#define AS_OFF  98304
#define VS_OFF  131072
#define AC_OFF  0
#define CC_OFF  32768
#define ATA_OFF 49664
#define ATV_OFF 58880
#define AWT_OFF 68096
#define VWT_OFF 77312
#define RED_OFF 86528

__global__ __launch_bounds__(512, 1) void kF(
    const float* __restrict__ Xa, const float* __restrict__ Xv,
    const _Float16* __restrict__ WaP, const _Float16* __restrict__ WvP,
    const float* __restrict__ ba, const float* __restrict__ bv,
    const _Float16* __restrict__ corrT, const _Float16* __restrict__ WbT,
    const float* __restrict__ bb, const float* __restrict__ gamma,
    const float* __restrict__ beta, float* __restrict__ out)
{
    extern __shared__ __align__(16) char sm[];
    char* Xsm = sm + XS_OFF;
    char* As_ = sm + AS_OFF;
    char* Vs_ = sm + VS_OFF;

    const int b = blockIdx.x;
    const int t = threadIdx.x, lane = t & 63, w = t >> 6;
    const int q = lane >> 4, lm = lane & 15;

    const float* Xa_b = Xa + (size_t)b * 49152;
    const float* Xv_b = Xv + (size_t)b * 49152;

    // swizzled addressing helpers (byteoff within row; XOR bits 4..6)
    auto swzX   = [](int row, int bo) { return row * 1536 + (bo ^ ((row & 7) << 4)); };
    auto swz512 = [](int row, int bo) { return row * 512  + (bo ^ ((row & 7) << 4)); };

    // ---------------- phase 1: projections ----------------
    f32x4 L[12];

    auto stage_load = [&](const float* src, int h) {
        #pragma unroll
        for (int i = 0; i < 12; ++i)
            L[i] = *reinterpret_cast<const f32x4*>(src + h * 24576 + (i * 512 + t) * 4);
    };
    auto stage_write = [&](int h) {
        #pragma unroll
        for (int i = 0; i < 12; ++i) {
            int e4 = i * 512 + t;            // f32x4 index within half
            int row = h * 32 + e4 / 192;     // 192 f32x4 per row
            int k = (e4 - (e4 / 192) * 192) * 4;
            f16x4 hv = __builtin_convertvector(L[i], f16x4);
            *reinterpret_cast<f16x4*>(Xsm + swzX(row, k * 2)) = hv;
        }
    };
    auto gemm = [&](const _Float16* WPz, char* dest, const float* bz, int h) {
        const int m2 = w & 1, ns = w >> 1;
        const int rowbase = h * 32 + m2 * 16;
        float bias4[4];
        #pragma unroll
        for (int nf = 0; nf < 4; ++nf)
            bias4[nf] = bz[ns * 64 + nf * 16 + lm];
        f32x4 a4[4] = {};
        #pragma unroll
        for (int ks = 0; ks < 24; ++ks) {
            f16x8 af = *reinterpret_cast<const f16x8*>(
                Xsm + swzX(rowbase + lm, ks * 64 + q * 16));
            #pragma unroll
            for (int nf = 0; nf < 4; ++nf) {
                f16x8 bf = *reinterpret_cast<const f16x8*>(
                    WPz + ((size_t)(ks * 16 + ns * 4 + nf) * 64 + lane) * 8);
                a4[nf] = __builtin_amdgcn_mfma_f32_16x16x32_f16(af, bf, a4[nf], 0, 0, 0);
            }
        }
        #pragma unroll
        for (int nf = 0; nf < 4; ++nf)
            #pragma unroll
            for (int r = 0; r < 4; ++r) {
                int rr = rowbase + q * 4 + r;
                int cc = ns * 64 + nf * 16 + lm;
                *reinterpret_cast<_Float16*>(dest + swz512(rr, cc * 2)) =
                    (_Float16)(a4[nf][r] + bias4[nf]);
            }
    };

    stage_load(Xa_b, 0);
    stage_write(0);
    __syncthreads();

    {
        const float*    srcs[4] = {Xa_b, Xv_b, Xv_b, nullptr};  // next-src for p=0..2
        const int       nh[4]   = {1, 0, 1, 0};
        #pragma unroll
        for (int p = 0; p < 4; ++p) {
            const _Float16* WPz = (p < 2) ? WaP : WvP;
            char*           dst = (p < 2) ? As_ : Vs_;
            const float*    bz  = (p < 2) ? ba  : bv;
            const int       ch  = p & 1;
            if (p < 3) stage_load(srcs[p], nh[p]);   // issue next-half HBM stream early
            gemm(WPz, dst, bz, ch);
            if (p < 3) stage_write(nh[p]);
            __syncthreads();
        }
    }

    // ---------------- phase B: ac = a @ corr (8 waves, e-slice 32) ----------------
    char* ACs = sm + AC_OFF;
    float*    cc_s  = (float*)(sm + CC_OFF);
    _Float16* attAT = (_Float16*)(sm + ATA_OFF);
    _Float16* attV  = (_Float16*)(sm + ATV_OFF);
    _Float16* awT   = (_Float16*)(sm + AWT_OFF);
    _Float16* vwT   = (_Float16*)(sm + VWT_OFF);
    float*    red   = (float*)(sm + RED_OFF);
    {
        f32x4 ab[4][2] = {};
        #pragma unroll
        for (int ks = 0; ks < 8; ++ks) {
            f16x8 af[4];
            #pragma unroll
            for (int mf = 0; mf < 4; ++mf)
                af[mf] = *reinterpret_cast<const f16x8*>(
                    As_ + swz512(mf * 16 + lm, ks * 64 + q * 16));
            #pragma unroll
            for (int nf = 0; nf < 2; ++nf) {
                int e = w * 32 + nf * 16 + lm;
                f16x8 bf = *reinterpret_cast<const f16x8*>(corrT + (size_t)e * 256 + ks * 32 + q * 8);
                #pragma unroll
                for (int mf = 0; mf < 4; ++mf)
                    ab[mf][nf] = __builtin_amdgcn_mfma_f32_16x16x32_f16(af[mf], bf, ab[mf][nf], 0, 0, 0);
            }
        }
        #pragma unroll
        for (int mf = 0; mf < 4; ++mf)
            #pragma unroll
            for (int nf = 0; nf < 2; ++nf)
                #pragma unroll
                for (int r = 0; r < 4; ++r) {
                    int rr = mf * 16 + 4 * q + r;
                    int cc = w * 32 + nf * 16 + lm;
                    *reinterpret_cast<_Float16*>(ACs + swz512(rr, cc * 2)) =
                        (_Float16)ab[mf][nf][r];
                }
    }
    __syncthreads();

    // ---------------- phase C: cc = ac @ v^T (8 waves: jstrip x mhalf) ----------------
    {
        int jst = w & 3, mh = w >> 2;
        f32x4 c2[2] = {};
        #pragma unroll
        for (int ks = 0; ks < 8; ++ks) {
            f16x8 bf = *reinterpret_cast<const f16x8*>(
                Vs_ + swz512(jst * 16 + lm, ks * 64 + q * 16));
            #pragma unroll
            for (int mi = 0; mi < 2; ++mi) {
                int mf = mh * 2 + mi;
                f16x8 af = *reinterpret_cast<const f16x8*>(
                    ACs + swz512(mf * 16 + lm, ks * 64 + q * 16));
                c2[mi] = __builtin_amdgcn_mfma_f32_16x16x32_f16(af, bf, c2[mi], 0, 0, 0);
            }
        }
        #pragma unroll
        for (int mi = 0; mi < 2; ++mi)
            #pragma unroll
            for (int r = 0; r < 4; ++r)
                cc_s[((mh * 2 + mi) * 16 + 4 * q + r) * 66 + jst * 16 + lm] = c2[mi][r];
    }
    __syncthreads();

    // ---------------- phase D: dual softmax (+I); threads<256, hoisted barriers ----------------
    {
        bool act = t < 256;
        int j = t & 63, seg = w & 3;
        float cm = 0.f, rm = 0.f;
        if (act) {
            float cmx = -1e30f, rmx = -1e30f;
            #pragma unroll
            for (int k = 0; k < 16; ++k) {
                int i = seg * 16 + k;
                cmx = fmaxf(cmx, cc_s[i * 66 + j]);
                rmx = fmaxf(rmx, cc_s[j * 66 + i]);
            }
            red[0 * 256 + seg * 64 + j] = cmx;
            red[2 * 256 + seg * 64 + j] = rmx;
        }
        __syncthreads();
        if (act) {
            cm = fmaxf(fmaxf(red[0 * 256 + 0 * 64 + j], red[0 * 256 + 1 * 64 + j]),
                       fmaxf(red[0 * 256 + 2 * 64 + j], red[0 * 256 + 3 * 64 + j]));
            rm = fmaxf(fmaxf(red[2 * 256 + 0 * 64 + j], red[2 * 256 + 1 * 64 + j]),
                       fmaxf(red[2 * 256 + 2 * 64 + j], red[2 * 256 + 3 * 64 + j]));
            float cs = 0.f, rs = 0.f;
            #pragma unroll
            for (int k = 0; k < 16; ++k) {
                int i = seg * 16 + k;
                cs += __expf(cc_s[i * 66 + j] - cm);
                rs += __expf(cc_s[j * 66 + i] - rm);
            }
            red[1 * 256 + seg * 64 + j] = cs;
            red[3 * 256 + seg * 64 + j] = rs;
        }
        __syncthreads();
        if (act) {
            float csum = red[1 * 256 + 0 * 64 + j] + red[1 * 256 + 1 * 64 + j] +
                         red[1 * 256 + 2 * 64 + j] + red[1 * 256 + 3 * 64 + j];
            float rsum = red[3 * 256 + 0 * 64 + j] + red[3 * 256 + 1 * 64 + j] +
                         red[3 * 256 + 2 * 64 + j] + red[3 * 256 + 3 * 64 + j];
            float cinv = 1.f / csum, rinv = 1.f / rsum;
            #pragma unroll
            for (int k = 0; k < 16; ++k) {
                int i = seg * 16 + k;
                float pa = __expf(cc_s[i * 66 + j] - cm) * cinv;
                if (i == j) pa += 1.f;
                attAT[j * 72 + i] = (_Float16)pa;
                float pv = __expf(cc_s[j * 66 + i] - rm) * rinv;
                if (i == j) pv += 1.f;
                attV[j * 72 + i] = (_Float16)pv;
            }
        }
    }
    __syncthreads();

    // ---------------- phase E: aw/vw (8 waves: isV x 16-col o-slice) ----------------
    {
        int isV = w >> 2, wcol = w & 3;
        const char* src = isV ? Vs_ : As_;
        const int doff = isV ? 256 : 0;
        int o = wcol * 16 + lm;
        f32x4 e4[4] = {};
        #pragma unroll
        for (int ks = 0; ks < 8; ++ks) {
            f16x8 bf = *reinterpret_cast<const f16x8*>(WbT + (size_t)o * 512 + doff + ks * 32 + q * 8);
            #pragma unroll
            for (int mf = 0; mf < 4; ++mf) {
                f16x8 af = *reinterpret_cast<const f16x8*>(
                    src + swz512(mf * 16 + lm, ks * 64 + q * 16));
                e4[mf] = __builtin_amdgcn_mfma_f32_16x16x32_f16(af, bf, e4[mf], 0, 0, 0);
            }
        }
        _Float16* dst = isV ? vwT : awT;
        #pragma unroll
        for (int mf = 0; mf < 4; ++mf)
            #pragma unroll
            for (int r = 0; r < 4; ++r)
                dst[(wcol * 16 + lm) * 72 + (mf * 16 + 4 * q + r)] = (_Float16)e4[mf][r];
    }
    __syncthreads();

    // ---------------- phase F+G: h = attA^T@aw + attV@vw; LN; ReLU (waves 0-3) ----------------
    if (w < 4) {
        f32x4 hacc[4] = {};
        #pragma unroll
        for (int kk = 0; kk < 2; ++kk) {
            f16x8 a1 = *reinterpret_cast<const f16x8*>(attAT + (16 * w + lm) * 72 + kk * 32 + q * 8);
            f16x8 a2 = *reinterpret_cast<const f16x8*>(attV  + (16 * w + lm) * 72 + kk * 32 + q * 8);
            #pragma unroll
            for (int nf = 0; nf < 4; ++nf) {
                f16x8 b1 = *reinterpret_cast<const f16x8*>(awT + (nf * 16 + lm) * 72 + kk * 32 + q * 8);
                f16x8 b2 = *reinterpret_cast<const f16x8*>(vwT + (nf * 16 + lm) * 72 + kk * 32 + q * 8);
                hacc[nf] = __builtin_amdgcn_mfma_f32_16x16x32_f16(a1, b1, hacc[nf], 0, 0, 0);
                hacc[nf] = __builtin_amdgcn_mfma_f32_16x16x32_f16(a2, b2, hacc[nf], 0, 0, 0);
            }
        }
        float bbv[4], gv[4], bev[4];
        #pragma unroll
        for (int nf = 0; nf < 4; ++nf) {
            int o = nf * 16 + lm;
            bbv[nf] = bb[o]; gv[nf] = gamma[o]; bev[nf] = beta[o];
        }
        #pragma unroll
        for (int r = 0; r < 4; ++r) {
            float vals[4]; float s1 = 0.f, s2 = 0.f;
            #pragma unroll
            for (int nf = 0; nf < 4; ++nf) {
                float hv = hacc[nf][r] + bbv[nf];
                vals[nf] = hv; s1 += hv; s2 += hv * hv;
            }
            #pragma unroll
            for (int m = 1; m < 16; m <<= 1) {
                s1 += __shfl_xor(s1, m, 64);
                s2 += __shfl_xor(s2, m, 64);
            }
            float mu = s1 * 0.015625f;
            float var = s2 * 0.015625f - mu * mu;
            float rstd = rsqrtf(var + 1e-5f);
            int s = 16 * w + 4 * q + r;
            float* orow = out + ((size_t)b * 64 + s) * 64;
            #pragma unroll
            for (int nf = 0; nf < 4; ++nf) {
                float y = (vals[nf] - mu) * rstd * gv[nf] + bev[nf];
                orow[nf * 16 + lm] = fmaxf(y, 0.f);
            }
        }
    }
}

// =========================================================
extern "C" void kernel_launch(void* const* d_in, const int* in_sizes, int n_in,
                              void* d_out, int out_size, void* d_ws, size_t ws_size,
                              hipStream_t stream) {
    const float* Xa    = (const float*)d_in[0];
    const float* Xv    = (const float*)d_in[1];
    const float* Wa    = (const float*)d_in[2];
    const float* ba    = (const float*)d_in[3];
    const float* Wv    = (const float*)d_in[4];
    const float* bv    = (const float*)d_in[5];
    const float* corr  = (const float*)d_in[6];
    const float* Wb    = (const float*)d_in[7];
    const float* bb    = (const float*)d_in[8];
    const float* gamma = (const float*)d_in[9];
    const float* beta  = (const float*)d_in[10];
    float* out = (float*)d_out;
    char* ws = (char*)d_ws;

    _Float16* WaP   = (_Float16*)(ws + WAP_OFF);
    _Float16* WvP   = (_Float16*)(ws + WVP_OFF);
    _Float16* corrT = (_Float16*)(ws + CORRT_OFF);
    _Float16* WbT   = (_Float16*)(ws + WBT_OFF);

    hipLaunchKernelGGL(k_prep, dim3(216), dim3(256), 0, stream,
                       Wa, Wv, corr, Wb, WaP, WvP, corrT, WbT);
    (void)hipFuncSetAttribute((const void*)kF,
                              hipFuncAttributeMaxDynamicSharedMemorySize, 163840);
    hipLaunchKernelGGL(kF, dim3(512), dim3(512), 163840, stream,
                       Xa, Xv, WaP, WvP, ba, bv, corrT, WbT, bb, gamma, beta, out);
}

// Round 10
// 89.542 us; speedup vs baseline: 1.2114x; 1.2114x over previous
//
#include <hip/hip_runtime.h>

typedef _Float16 f16x8 __attribute__((ext_vector_type(8)));
typedef _Float16 f16x4 __attribute__((ext_vector_type(4)));
typedef float    f32x4 __attribute__((ext_vector_type(4)));

// ---------------- workspace layout (bytes) ----------------
#define A16_OFF   0u
#define V16_OFF   16777216u
#define WAP_OFF   33554432u   // fragment-packed Wa fp16: 24*16*64*8*2 = 393216 B
#define WVP_OFF   33947648u
#define CORRT_OFF 34340864u
#define WBT_OFF   34471936u

#define SCHED0() __builtin_amdgcn_sched_barrier(0)
#define SBAR()   __builtin_amdgcn_s_barrier()

__device__ __forceinline__ void gl_lds16(const void* g, void* l) {
    __builtin_amdgcn_global_load_lds(
        (const __attribute__((address_space(1))) void*)g,
        (__attribute__((address_space(3))) void*)l, 16, 0, 0);
}

// =========================================================
// k_prep: (blocks 0..191) Wa/Wv [768,256] fp32 -> MFMA-fragment-
//  packed fp16: fragment (kc,nb) = 64 lanes x 16B contiguous, lane
//  l=(q,lm) holds W[kc*32+q*8+e][nb*16+lm].
//  (blocks 192..215) transpose+cvt corr -> corrT, Wb -> WbT.
// =========================================================
__global__ __launch_bounds__(256) void k_prep(
    const float* __restrict__ Wa, const float* __restrict__ Wv,
    const float* __restrict__ corr, const float* __restrict__ Wb,
    _Float16* __restrict__ WaP, _Float16* __restrict__ WvP,
    _Float16* __restrict__ corrT, _Float16* __restrict__ WbT)
{
    __shared__ _Float16 tile[64][72];
    int bid = blockIdx.x;
    int t = threadIdx.x;
    if (bid < 192) {
        int z = bid >= 96;
        int b = z ? bid - 96 : bid;
        const float* W = z ? Wv : Wa;
        _Float16* P = z ? WvP : WaP;
        int kc = b >> 2, nbg = b & 3;
        int l = t & 63, sub = t >> 6;
        int nb = nbg * 4 + sub;
        int q = l >> 4, lm = l & 15;
        int k0 = kc * 32 + q * 8;
        int n = nb * 16 + lm;
        _Float16 tmp[8];
        #pragma unroll
        for (int e = 0; e < 8; ++e)
            tmp[e] = (_Float16)W[(size_t)(k0 + e) * 256 + n];
        *reinterpret_cast<f16x8*>(P + ((size_t)(kc * 16 + nb) * 64 + l) * 8) =
            *reinterpret_cast<const f16x8*>(tmp);
    } else {
        int b2 = bid - 192;
        const float* src; _Float16* dst; int R, C, tr, tc;
        if (b2 < 16) { src = corr; dst = corrT; R = 256; C = 256; tr = b2 >> 2; tc = b2 & 3; }
        else         { src = Wb;   dst = WbT;   R = 512; C = 64;  tr = b2 - 16; tc = 0;      }
        int r0 = tr * 64, c0 = tc * 64;
        #pragma unroll
        for (int it = 0; it < 16; ++it) {
            int idx = t + it * 256;
            int r = idx >> 6, c = idx & 63;
            tile[r][c] = (_Float16)src[(size_t)(r0 + r) * C + (c0 + c)];
        }
        __syncthreads();
        #pragma unroll
        for (int it = 0; it < 16; ++it) {
            int idx = t + it * 256;
            int c = idx >> 6, r = idx & 63;
            dst[(size_t)(c0 + c) * R + (r0 + r)] = tile[r][c];
        }
    }
}

// =========================================================
// k_proj v10: v6's counted-vmcnt LDS pipeline, oversubscribed grid.
//  BM=64, BN=256, BK=32; 256 thr (4 waves, 2Mx2N; wave tile 32x128).
//  1024 blocks = 4 blocks/CU queued, 3 resident (48 KB LDS each) --
//  staggered execution replaces v6's exact-fit lockstep.
//  LDS: A fp32 dbuf 2x8K (xor-swizzled via source) + B fp16 dbuf
//  2x16K (fragment-packed linear) = 48 KB.
//  Per step: [A frags + B frags + 32 MFMA] lgkm0 SBAR
//            [stage ks+2: 6 DMA/wave] vmcnt(6) SBAR.
// =========================================================
__global__ __launch_bounds__(256, 3) void k_proj(
    const float* __restrict__ Xa, const float* __restrict__ Xv,
    const _Float16* __restrict__ WaP, const _Float16* __restrict__ WvP,
    const float* __restrict__ ba, const float* __restrict__ bv,
    _Float16* __restrict__ Aout, _Float16* __restrict__ Vout)
{
    __shared__ __align__(16) char smem[49152];  // [0,16K): A dbuf  [16K,48K): B dbuf

    // bijective XCD-chunked swizzle: xcd = bid&7 owns 128 consecutive tiles
    const int bid = blockIdx.x;
    const int lin = (bid & 7) * 128 + (bid >> 3);   // 0..1023
    const int z = lin >> 9, mb = lin & 511;
    const float*    X    = z ? Xv  : Xa;
    const _Float16* WP   = z ? WvP : WaP;
    const float*    bias = z ? bv  : ba;
    _Float16*       Out  = z ? Vout : Aout;
    const int m0 = mb * 64;

    const int t = threadIdx.x, lane = t & 63, w = t >> 6;
    const int wr = w >> 1, wc = w & 1;          // wave tile: rows 32*wr, cols 128*wc
    const int q = lane >> 4, lm = lane & 15;

    f32x4 acc[2][8] = {};

    auto stageA = [&](int ks, int buf) {
        char* base = smem + buf * 8192;
        #pragma unroll
        for (int it = 0; it < 2; ++it) {
            int idx0 = it * 256 + w * 64;       // wave-uniform chunk base
            int idx = idx0 + lane;              // 0..511: r=idx>>3, c=idx&7
            int r = idx >> 3, c = idx & 7;
            int gc = c ^ (r & 7);               // inverse swizzle on global source
            gl_lds16(X + (size_t)(m0 + r) * 768 + ks * 32 + gc * 4,
                     base + idx0 * 16);
        }
    };
    auto stageB = [&](int ks, int buf) {
        char* base = smem + 16384 + buf * 16384;
        #pragma unroll
        for (int it = 0; it < 4; ++it) {
            int idx0 = it * 256 + w * 64;
            gl_lds16(WP + ((size_t)ks * 1024 + idx0 + lane) * 8,
                     base + idx0 * 16);
        }
    };

    // prologue: two tiles in flight; confirm tile 0 only (vmcnt(6))
    stageA(0, 0); stageB(0, 0);
    stageA(1, 1); stageB(1, 1);
    asm volatile("s_waitcnt vmcnt(6)" ::: "memory"); SCHED0();
    SBAR();

    for (int ks = 0; ks < 24; ++ks) {
        const int cur = ks & 1;
        const char* Ac = smem + cur * 8192;
        const char* Bc = smem + 16384 + cur * 16384;

        // ---- A fragments (fp32 in LDS -> fp16 regs) ----
        f16x8 af[2];
        #pragma unroll
        for (int mf = 0; mf < 2; ++mf) {
            int r = wr * 32 + mf * 16 + lm;
            const char* base = Ac + r * 128;
            int c0 = (2 * q) ^ (r & 7);
            int c1 = (2 * q + 1) ^ (r & 7);
            f32x4 lo = *reinterpret_cast<const f32x4*>(base + c0 * 16);
            f32x4 hi = *reinterpret_cast<const f32x4*>(base + c1 * 16);
            f16x4 l4 = __builtin_convertvector(lo, f16x4);
            f16x4 h4 = __builtin_convertvector(hi, f16x4);
            af[mf] = __builtin_shufflevector(l4, h4, 0, 1, 2, 3, 4, 5, 6, 7);
        }
        // ---- B frag + MFMA interleaved ----
        #pragma unroll
        for (int nf = 0; nf < 8; ++nf) {
            int nb = wc * 8 + nf;
            f16x8 bf = *reinterpret_cast<const f16x8*>(Bc + (nb * 64 + lane) * 16);
            acc[0][nf] = __builtin_amdgcn_mfma_f32_16x16x32_f16(af[0], bf, acc[0][nf], 0, 0, 0);
            acc[1][nf] = __builtin_amdgcn_mfma_f32_16x16x32_f16(af[1], bf, acc[1][nf], 0, 0, 0);
        }
        asm volatile("s_waitcnt lgkmcnt(0)" ::: "memory"); SCHED0();
        SBAR();                                  // all waves done reading buf[cur]
        // ---- refill freed buffer (lands ~1.8 steps later) ----
        if (ks + 2 < 24) { stageA(ks + 2, cur); stageB(ks + 2, cur); }
        // ---- counted wait: tile ks+1 ready, tile ks+2 stays in flight ----
        if (ks < 22)      { asm volatile("s_waitcnt vmcnt(6)" ::: "memory"); }
        else if (ks == 22){ asm volatile("s_waitcnt vmcnt(0)" ::: "memory"); }
        SCHED0();
        if (ks < 23) SBAR();
    }

    // ---- epilogue: acc (+bias) -> LDS fp16 [64][256] -> coalesced stores ----
    float biasv[8];
    #pragma unroll
    for (int nf = 0; nf < 8; ++nf)
        biasv[nf] = bias[wc * 128 + nf * 16 + lm];

    __syncthreads();
    _Float16* Cs = (_Float16*)smem;   // 32 KB = 64 x 256 fp16
    #pragma unroll
    for (int mf = 0; mf < 2; ++mf)
        #pragma unroll
        for (int nf = 0; nf < 8; ++nf)
            #pragma unroll
            for (int r = 0; r < 4; ++r)
                Cs[(wr * 32 + mf * 16 + q * 4 + r) * 256 + wc * 128 + nf * 16 + lm] =
                    (_Float16)(acc[mf][nf][r] + biasv[nf]);
    __syncthreads();
    #pragma unroll
    for (int it = 0; it < 8; ++it) {
        int idx = t + it * 256;
        int row = idx >> 5, c = idx & 31;
        f16x8 vv = *reinterpret_cast<const f16x8*>(Cs + row * 256 + c * 8);
        *reinterpret_cast<f16x8*>(Out + (size_t)(m0 + row) * 256 + c * 8) = vv;
    }
}

// =========================================================
// k_fuse: per-batch (512 blocks, 256 thr = 4 waves) — unchanged
// =========================================================
#define SM_A    0u
#define SM_V    33792u
#define SM_AC   67584u
#define SM_CC   101376u
#define SM_ATA  118272u
#define SM_ATV  127488u
#define SM_AWT  136704u
#define SM_VWT  145920u
#define SM_RED  155136u
#define SM_TOTAL 159232u

__global__ __launch_bounds__(256) void k_fuse(
    const _Float16* __restrict__ A16, const _Float16* __restrict__ V16,
    const _Float16* __restrict__ corrT, const _Float16* __restrict__ WbT,
    const float* __restrict__ bb, const float* __restrict__ gamma,
    const float* __restrict__ beta, float* __restrict__ out)
{
    extern __shared__ char sm[];
    _Float16* a_s   = (_Float16*)(sm + SM_A);
    _Float16* v_s   = (_Float16*)(sm + SM_V);
    _Float16* ac_s  = (_Float16*)(sm + SM_AC);
    float*    cc_s  = (float*)(sm + SM_CC);
    _Float16* attAT = (_Float16*)(sm + SM_ATA);
    _Float16* attV  = (_Float16*)(sm + SM_ATV);
    _Float16* awT   = (_Float16*)(sm + SM_AWT);
    _Float16* vwT   = (_Float16*)(sm + SM_VWT);
    float*    red   = (float*)(sm + SM_RED);

    const int b = blockIdx.x;
    const int t = threadIdx.x, lane = t & 63, w = t >> 6;
    const int q = lane >> 4, lm = lane & 15;

    const _Float16* Ab = A16 + (size_t)b * 64 * 256;
    const _Float16* Vb = V16 + (size_t)b * 64 * 256;
    #pragma unroll
    for (int it = 0; it < 8; ++it) {
        int idx = t + it * 256;
        int row = idx >> 5, kc = idx & 31;
        *reinterpret_cast<f16x8*>(a_s + row * 264 + kc * 8) =
            *reinterpret_cast<const f16x8*>(Ab + row * 256 + kc * 8);
        *reinterpret_cast<f16x8*>(v_s + row * 264 + kc * 8) =
            *reinterpret_cast<const f16x8*>(Vb + row * 256 + kc * 8);
    }
    __syncthreads();

    // ac = a @ corr
    {
        f32x4 acc[4][4] = {};
        for (int ks = 0; ks < 8; ++ks) {
            f16x8 af[4];
            #pragma unroll
            for (int mf = 0; mf < 4; ++mf)
                af[mf] = *reinterpret_cast<const f16x8*>(a_s + (mf * 16 + lm) * 264 + ks * 32 + q * 8);
            #pragma unroll
            for (int nf = 0; nf < 4; ++nf) {
                int e = w * 64 + nf * 16 + lm;
                f16x8 bf = *reinterpret_cast<const f16x8*>(corrT + (size_t)e * 256 + ks * 32 + q * 8);
                #pragma unroll
                for (int mf = 0; mf < 4; ++mf)
                    acc[mf][nf] = __builtin_amdgcn_mfma_f32_16x16x32_f16(af[mf], bf, acc[mf][nf], 0, 0, 0);
            }
        }
        #pragma unroll
        for (int mf = 0; mf < 4; ++mf)
            #pragma unroll
            for (int nf = 0; nf < 4; ++nf)
                #pragma unroll
                for (int r = 0; r < 4; ++r)
                    ac_s[(mf * 16 + 4 * q + r) * 264 + (w * 64 + nf * 16 + lm)] = (_Float16)acc[mf][nf][r];
    }
    __syncthreads();

    // cc = ac @ v^T
    {
        f32x4 acc[4] = {};
        for (int ks = 0; ks < 8; ++ks) {
            f16x8 bf = *reinterpret_cast<const f16x8*>(v_s + (w * 16 + lm) * 264 + ks * 32 + q * 8);
            #pragma unroll
            for (int mf = 0; mf < 4; ++mf) {
                f16x8 af = *reinterpret_cast<const f16x8*>(ac_s + (mf * 16 + lm) * 264 + ks * 32 + q * 8);
                acc[mf] = __builtin_amdgcn_mfma_f32_16x16x32_f16(af, bf, acc[mf], 0, 0, 0);
            }
        }
        #pragma unroll
        for (int mf = 0; mf < 4; ++mf)
            #pragma unroll
            for (int r = 0; r < 4; ++r)
                cc_s[(mf * 16 + 4 * q + r) * 66 + (w * 16 + lm)] = acc[mf][r];
    }
    __syncthreads();

    // dual softmax (+identity)
    {
        int j = t & 63, seg = w;
        float cmx = -1e30f, rmx = -1e30f;
        #pragma unroll
        for (int k = 0; k < 16; ++k) {
            int i = seg * 16 + k;
            cmx = fmaxf(cmx, cc_s[i * 66 + j]);
            rmx = fmaxf(rmx, cc_s[j * 66 + i]);
        }
        red[0 * 256 + seg * 64 + j] = cmx;
        red[2 * 256 + seg * 64 + j] = rmx;
        __syncthreads();
        float cm = fmaxf(fmaxf(red[0 * 256 + 0 * 64 + j], red[0 * 256 + 1 * 64 + j]),
                         fmaxf(red[0 * 256 + 2 * 64 + j], red[0 * 256 + 3 * 64 + j]));
        float rm = fmaxf(fmaxf(red[2 * 256 + 0 * 64 + j], red[2 * 256 + 1 * 64 + j]),
                         fmaxf(red[2 * 256 + 2 * 64 + j], red[2 * 256 + 3 * 64 + j]));
        float cs = 0.f, rs = 0.f;
        #pragma unroll
        for (int k = 0; k < 16; ++k) {
            int i = seg * 16 + k;
            cs += __expf(cc_s[i * 66 + j] - cm);
            rs += __expf(cc_s[j * 66 + i] - rm);
        }
        red[1 * 256 + seg * 64 + j] = cs;
        red[3 * 256 + seg * 64 + j] = rs;
        __syncthreads();
        float csum = red[1 * 256 + 0 * 64 + j] + red[1 * 256 + 1 * 64 + j] +
                     red[1 * 256 + 2 * 64 + j] + red[1 * 256 + 3 * 64 + j];
        float rsum = red[3 * 256 + 0 * 64 + j] + red[3 * 256 + 1 * 64 + j] +
                     red[3 * 256 + 2 * 64 + j] + red[3 * 256 + 3 * 64 + j];
        float cinv = 1.f / csum, rinv = 1.f / rsum;
        #pragma unroll
        for (int k = 0; k < 16; ++k) {
            int i = seg * 16 + k;
            float pa = __expf(cc_s[i * 66 + j] - cm) * cinv;
            if (i == j) pa += 1.f;
            attAT[j * 72 + i] = (_Float16)pa;
            float pv = __expf(cc_s[j * 66 + i] - rm) * rinv;
            if (i == j) pv += 1.f;
            attV[j * 72 + i] = (_Float16)pv;
        }
    }

    // aw = a@Wb_top (waves 0,1), vw = v@Wb_bot (waves 2,3)
    {
        int isV = w >> 1, wcol = w & 1;
        const _Float16* src = isV ? v_s : a_s;
        const int doff = isV ? 256 : 0;
        f32x4 acc[4][2] = {};
        for (int ks = 0; ks < 8; ++ks) {
            f16x8 af[4];
            #pragma unroll
            for (int mf = 0; mf < 4; ++mf)
                af[mf] = *reinterpret_cast<const f16x8*>(src + (mf * 16 + lm) * 264 + ks * 32 + q * 8);
            #pragma unroll
            for (int nf = 0; nf < 2; ++nf) {
                int o = wcol * 32 + nf * 16 + lm;
                f16x8 bf = *reinterpret_cast<const f16x8*>(WbT + (size_t)o * 512 + doff + ks * 32 + q * 8);
                #pragma unroll
                for (int mf = 0; mf < 4; ++mf)
                    acc[mf][nf] = __builtin_amdgcn_mfma_f32_16x16x32_f16(af[mf], bf, acc[mf][nf], 0, 0, 0);
            }
        }
        _Float16* dst = isV ? vwT : awT;
        #pragma unroll
        for (int mf = 0; mf < 4; ++mf)
            #pragma unroll
            for (int nf = 0; nf < 2; ++nf)
                #pragma unroll
                for (int r = 0; r < 4; ++r)
                    dst[(wcol * 32 + nf * 16 + lm) * 72 + (mf * 16 + 4 * q + r)] = (_Float16)acc[mf][nf][r];
    }
    __syncthreads();

    // h = attA^T@aw + attV@vw
    f32x4 hacc[4] = {};
    #pragma unroll
    for (int kk = 0; kk < 2; ++kk) {
        f16x8 a1 = *reinterpret_cast<const f16x8*>(attAT + (16 * w + lm) * 72 + kk * 32 + q * 8);
        f16x8 a2 = *reinterpret_cast<const f16x8*>(attV  + (16 * w + lm) * 72 + kk * 32 + q * 8);
        #pragma unroll
        for (int nf = 0; nf < 4; ++nf) {
            f16x8 b1 = *reinterpret_cast<const f16x8*>(awT + (nf * 16 + lm) * 72 + kk * 32 + q * 8);
            f16x8 b2 = *reinterpret_cast<const f16x8*>(vwT + (nf * 16 + lm) * 72 + kk * 32 + q * 8);
            hacc[nf] = __builtin_amdgcn_mfma_f32_16x16x32_f16(a1, b1, hacc[nf], 0, 0, 0);
            hacc[nf] = __builtin_amdgcn_mfma_f32_16x16x32_f16(a2, b2, hacc[nf], 0, 0, 0);
        }
    }

    // +bb, LayerNorm, ReLU, store
    {
        float bbv[4], gv[4], bev[4];
        #pragma unroll
        for (int nf = 0; nf < 4; ++nf) {
            int o = nf * 16 + lm;
            bbv[nf] = bb[o]; gv[nf] = gamma[o]; bev[nf] = beta[o];
        }
        #pragma unroll
        for (int r = 0; r < 4; ++r) {
            float vals[4]; float s1 = 0.f, s2 = 0.f;
            #pragma unroll
            for (int nf = 0; nf < 4; ++nf) {
                float hv = hacc[nf][r] + bbv[nf];
                vals[nf] = hv; s1 += hv; s2 += hv * hv;
            }
            #pragma unroll
            for (int m = 1; m < 16; m <<= 1) {
                s1 += __shfl_xor(s1, m, 64);
                s2 += __shfl_xor(s2, m, 64);
            }
            float mu = s1 * 0.015625f;
            float var = s2 * 0.015625f - mu * mu;
            float rstd = rsqrtf(var + 1e-5f);
            int s = 16 * w + 4 * q + r;
            float* orow = out + ((size_t)b * 64 + s) * 64;
            #pragma unroll
            for (int nf = 0; nf < 4; ++nf) {
                float y = (vals[nf] - mu) * rstd * gv[nf] + bev[nf];
                orow[nf * 16 + lm] = fmaxf(y, 0.f);
            }
        }
    }
}

// =========================================================
extern "C" void kernel_launch(void* const* d_in, const int* in_sizes, int n_in,
                              void* d_out, int out_size, void* d_ws, size_t ws_size,
                              hipStream_t stream) {
    const float* Xa    = (const float*)d_in[0];
    const float* Xv    = (const float*)d_in[1];
    const float* Wa    = (const float*)d_in[2];
    const float* ba    = (const float*)d_in[3];
    const float* Wv    = (const float*)d_in[4];
    const float* bv    = (const float*)d_in[5];
    const float* corr  = (const float*)d_in[6];
    const float* Wb    = (const float*)d_in[7];
    const float* bb    = (const float*)d_in[8];
    const float* gamma = (const float*)d_in[9];
    const float* beta  = (const float*)d_in[10];
    float* out = (float*)d_out;
    char* ws = (char*)d_ws;

    _Float16* a16   = (_Float16*)(ws + A16_OFF);
    _Float16* v16   = (_Float16*)(ws + V16_OFF);
    _Float16* WaP   = (_Float16*)(ws + WAP_OFF);
    _Float16* WvP   = (_Float16*)(ws + WVP_OFF);
    _Float16* corrT = (_Float16*)(ws + CORRT_OFF);
    _Float16* WbT   = (_Float16*)(ws + WBT_OFF);

    hipLaunchKernelGGL(k_prep, dim3(216), dim3(256), 0, stream,
                       Wa, Wv, corr, Wb, WaP, WvP, corrT, WbT);
    hipLaunchKernelGGL(k_proj, dim3(1024), dim3(256), 0, stream,
                       Xa, Xv, WaP, WvP, ba, bv, a16, v16);
    (void)hipFuncSetAttribute((const void*)k_fuse,
                              hipFuncAttributeMaxDynamicSharedMemorySize, SM_TOTAL);
    hipLaunchKernelGGL(k_fuse, dim3(512), dim3(256), SM_TOTAL, stream,
                       a16, v16, corrT, WbT, bb, gamma, beta, out);
}

// Round 11
// 85.903 us; speedup vs baseline: 1.2627x; 1.0424x over previous
//
#include <hip/hip_runtime.h>

typedef _Float16 f16x8 __attribute__((ext_vector_type(8)));
typedef _Float16 f16x4 __attribute__((ext_vector_type(4)));
typedef float    f32x4 __attribute__((ext_vector_type(4)));

// ---------------- workspace layout (bytes) ----------------
#define A16_OFF   0u
#define V16_OFF   16777216u
#define WAP_OFF   33554432u   // fragment-packed Wa fp16: 24*16*64*8*2 = 393216 B
#define WVP_OFF   33947648u
#define CORRT_OFF 34340864u
#define WBT_OFF   34471936u

#define SCHED0() __builtin_amdgcn_sched_barrier(0)
#define SBAR()   __builtin_amdgcn_s_barrier()

__device__ __forceinline__ void gl_lds16(const void* g, void* l) {
    __builtin_amdgcn_global_load_lds(
        (const __attribute__((address_space(1))) void*)g,
        (__attribute__((address_space(3))) void*)l, 16, 0, 0);
}

// =========================================================
// k_prep: (blocks 0..191) Wa/Wv [768,256] fp32 -> MFMA-fragment-
//  packed fp16: fragment (kc,nb) = 64 lanes x 16B contiguous, lane
//  l=(q,lm) holds W[kc*32+q*8+e][nb*16+lm].
//  (blocks 192..215) transpose+cvt corr -> corrT, Wb -> WbT.
// =========================================================
__global__ __launch_bounds__(256) void k_prep(
    const float* __restrict__ Wa, const float* __restrict__ Wv,
    const float* __restrict__ corr, const float* __restrict__ Wb,
    _Float16* __restrict__ WaP, _Float16* __restrict__ WvP,
    _Float16* __restrict__ corrT, _Float16* __restrict__ WbT)
{
    __shared__ _Float16 tile[64][72];
    int bid = blockIdx.x;
    int t = threadIdx.x;
    if (bid < 192) {
        int z = bid >= 96;
        int b = z ? bid - 96 : bid;
        const float* W = z ? Wv : Wa;
        _Float16* P = z ? WvP : WaP;
        int kc = b >> 2, nbg = b & 3;
        int l = t & 63, sub = t >> 6;
        int nb = nbg * 4 + sub;
        int q = l >> 4, lm = l & 15;
        int k0 = kc * 32 + q * 8;
        int n = nb * 16 + lm;
        _Float16 tmp[8];
        #pragma unroll
        for (int e = 0; e < 8; ++e)
            tmp[e] = (_Float16)W[(size_t)(k0 + e) * 256 + n];
        *reinterpret_cast<f16x8*>(P + ((size_t)(kc * 16 + nb) * 64 + l) * 8) =
            *reinterpret_cast<const f16x8*>(tmp);
    } else {
        int b2 = bid - 192;
        const float* src; _Float16* dst; int R, C, tr, tc;
        if (b2 < 16) { src = corr; dst = corrT; R = 256; C = 256; tr = b2 >> 2; tc = b2 & 3; }
        else         { src = Wb;   dst = WbT;   R = 512; C = 64;  tr = b2 - 16; tc = 0;      }
        int r0 = tr * 64, c0 = tc * 64;
        #pragma unroll
        for (int it = 0; it < 16; ++it) {
            int idx = t + it * 256;
            int r = idx >> 6, c = idx & 63;
            tile[r][c] = (_Float16)src[(size_t)(r0 + r) * C + (c0 + c)];
        }
        __syncthreads();
        #pragma unroll
        for (int it = 0; it < 16; ++it) {
            int idx = t + it * 256;
            int c = idx >> 6, r = idx & 63;
            dst[(size_t)(c0 + c) * R + (r0 + r)] = tile[r][c];
        }
    }
}

// =========================================================
// k_proj v11: BM=256 to amortize the B re-stream (total staged
//  bytes 594 -> 299 MB; the v10 counters showed the kernel is at
//  the ~6.7 TB/s aggregate VMEM->LDS delivery ceiling, so time
//  should scale with staged bytes).
//  BM=256, BN=256, BK=32; 512 thr (8 waves, 4Mx2N; wave 64x128).
//  LDS (dynamic 96 KB): A fp32 dbuf 2x32K (xor-swizzle via source),
//  B fp16 dbuf 2x16K (fragment-packed linear). 256 blocks (1/CU).
//  Per step: [A frags + B frags + 32 MFMA] lgkm0 SBAR
//            [stage ks+2: 6 DMA/wave] vmcnt(6) SBAR.
// =========================================================
__global__ __launch_bounds__(512, 1) void k_proj(
    const float* __restrict__ Xa, const float* __restrict__ Xv,
    const _Float16* __restrict__ WaP, const _Float16* __restrict__ WvP,
    const float* __restrict__ ba, const float* __restrict__ bv,
    _Float16* __restrict__ Aout, _Float16* __restrict__ Vout)
{
    extern __shared__ __align__(16) char smem[];  // [0,64K): A dbuf  [64K,96K): B dbuf

    // bijective XCD-chunked swizzle for 256 blocks (8 x 32)
    const int bid = blockIdx.x;
    const int lin = (bid & 7) * 32 + (bid >> 3);   // 0..255
    const int z = lin >> 7, mb = lin & 127;
    const float*    X    = z ? Xv  : Xa;
    const _Float16* WP   = z ? WvP : WaP;
    const float*    bias = z ? bv  : ba;
    _Float16*       Out  = z ? Vout : Aout;
    const int m0 = mb * 256;

    const int t = threadIdx.x, lane = t & 63, w = t >> 6;
    const int wr = w >> 1, wc = w & 1;          // wave tile: rows 64*wr, cols 128*wc
    const int q = lane >> 4, lm = lane & 15;

    f32x4 acc[4][8] = {};

    auto stageA = [&](int ks, int buf) {
        char* base = smem + buf * 32768;
        #pragma unroll
        for (int it = 0; it < 4; ++it) {
            int idx0 = it * 512 + w * 64;       // wave-uniform chunk base
            int idx = idx0 + lane;              // 0..2047: r=idx>>3, c=idx&7
            int r = idx >> 3, c = idx & 7;
            int gc = c ^ (r & 7);               // inverse swizzle on global source
            gl_lds16(X + (size_t)(m0 + r) * 768 + ks * 32 + gc * 4,
                     base + idx0 * 16);
        }
    };
    auto stageB = [&](int ks, int buf) {
        char* base = smem + 65536 + buf * 16384;
        #pragma unroll
        for (int it = 0; it < 2; ++it) {
            int idx0 = it * 512 + w * 64;
            gl_lds16(WP + ((size_t)ks * 1024 + idx0 + lane) * 8,
                     base + idx0 * 16);
        }
    };

    // prologue: two tiles in flight; confirm tile 0 only (vmcnt(6))
    stageA(0, 0); stageB(0, 0);
    stageA(1, 1); stageB(1, 1);
    asm volatile("s_waitcnt vmcnt(6)" ::: "memory"); SCHED0();
    SBAR();

    for (int ks = 0; ks < 24; ++ks) {
        const int cur = ks & 1;
        const char* Ac = smem + cur * 32768;
        const char* Bc = smem + 65536 + cur * 16384;

        // ---- A fragments (fp32 in LDS -> fp16 regs) ----
        f16x8 af[4];
        #pragma unroll
        for (int mf = 0; mf < 4; ++mf) {
            int r = wr * 64 + mf * 16 + lm;
            const char* base = Ac + r * 128;
            int c0 = (2 * q) ^ (r & 7);
            int c1 = (2 * q + 1) ^ (r & 7);
            f32x4 lo = *reinterpret_cast<const f32x4*>(base + c0 * 16);
            f32x4 hi = *reinterpret_cast<const f32x4*>(base + c1 * 16);
            f16x4 l4 = __builtin_convertvector(lo, f16x4);
            f16x4 h4 = __builtin_convertvector(hi, f16x4);
            af[mf] = __builtin_shufflevector(l4, h4, 0, 1, 2, 3, 4, 5, 6, 7);
        }
        // ---- B frag + MFMA interleaved ----
        #pragma unroll
        for (int nf = 0; nf < 8; ++nf) {
            int nb = wc * 8 + nf;
            f16x8 bf = *reinterpret_cast<const f16x8*>(Bc + (nb * 64 + lane) * 16);
            #pragma unroll
            for (int mf = 0; mf < 4; ++mf)
                acc[mf][nf] = __builtin_amdgcn_mfma_f32_16x16x32_f16(af[mf], bf, acc[mf][nf], 0, 0, 0);
        }
        asm volatile("s_waitcnt lgkmcnt(0)" ::: "memory"); SCHED0();
        SBAR();                                  // all waves done reading buf[cur]
        // ---- refill freed buffer (lands ~1.8 steps later) ----
        if (ks + 2 < 24) { stageA(ks + 2, cur); stageB(ks + 2, cur); }
        // ---- counted wait: tile ks+1 ready, tile ks+2 stays in flight ----
        if (ks < 22)      { asm volatile("s_waitcnt vmcnt(6)" ::: "memory"); }
        else if (ks == 22){ asm volatile("s_waitcnt vmcnt(0)" ::: "memory"); }
        SCHED0();
        if (ks < 23) SBAR();
    }

    // ---- epilogue: two 128-row halves through 64 KB of LDS ----
    float biasv[8];
    #pragma unroll
    for (int nf = 0; nf < 8; ++nf)
        biasv[nf] = bias[wc * 128 + nf * 16 + lm];

    _Float16* Cs = (_Float16*)smem;   // 64 KB = 128 x 256 fp16
    #pragma unroll
    for (int h = 0; h < 2; ++h) {
        __syncthreads();
        if ((wr >> 1) == h) {
            int rbase = (wr & 1) * 64;           // local row within half
            #pragma unroll
            for (int mf = 0; mf < 4; ++mf)
                #pragma unroll
                for (int nf = 0; nf < 8; ++nf)
                    #pragma unroll
                    for (int r = 0; r < 4; ++r)
                        Cs[(rbase + mf * 16 + q * 4 + r) * 256 + wc * 128 + nf * 16 + lm] =
                            (_Float16)(acc[mf][nf][r] + biasv[nf]);
        }
        __syncthreads();
        #pragma unroll
        for (int it = 0; it < 8; ++it) {
            int idx = t + it * 512;
            int row = idx >> 5, c = idx & 31;
            f16x8 vv = *reinterpret_cast<const f16x8*>(Cs + row * 256 + c * 8);
            *reinterpret_cast<f16x8*>(Out + (size_t)(m0 + h * 128 + row) * 256 + c * 8) = vv;
        }
    }
}

// =========================================================
// k_fuse: per-batch (512 blocks, 256 thr = 4 waves) — unchanged
// =========================================================
#define SM_A    0u
#define SM_V    33792u
#define SM_AC   67584u
#define SM_CC   101376u
#define SM_ATA  118272u
#define SM_ATV  127488u
#define SM_AWT  136704u
#define SM_VWT  145920u
#define SM_RED  155136u
#define SM_TOTAL 159232u

__global__ __launch_bounds__(256) void k_fuse(
    const _Float16* __restrict__ A16, const _Float16* __restrict__ V16,
    const _Float16* __restrict__ corrT, const _Float16* __restrict__ WbT,
    const float* __restrict__ bb, const float* __restrict__ gamma,
    const float* __restrict__ beta, float* __restrict__ out)
{
    extern __shared__ char sm[];
    _Float16* a_s   = (_Float16*)(sm + SM_A);
    _Float16* v_s   = (_Float16*)(sm + SM_V);
    _Float16* ac_s  = (_Float16*)(sm + SM_AC);
    float*    cc_s  = (float*)(sm + SM_CC);
    _Float16* attAT = (_Float16*)(sm + SM_ATA);
    _Float16* attV  = (_Float16*)(sm + SM_ATV);
    _Float16* awT   = (_Float16*)(sm + SM_AWT);
    _Float16* vwT   = (_Float16*)(sm + SM_VWT);
    float*    red   = (float*)(sm + SM_RED);

    const int b = blockIdx.x;
    const int t = threadIdx.x, lane = t & 63, w = t >> 6;
    const int q = lane >> 4, lm = lane & 15;

    const _Float16* Ab = A16 + (size_t)b * 64 * 256;
    const _Float16* Vb = V16 + (size_t)b * 64 * 256;
    #pragma unroll
    for (int it = 0; it < 8; ++it) {
        int idx = t + it * 256;
        int row = idx >> 5, kc = idx & 31;
        *reinterpret_cast<f16x8*>(a_s + row * 264 + kc * 8) =
            *reinterpret_cast<const f16x8*>(Ab + row * 256 + kc * 8);
        *reinterpret_cast<f16x8*>(v_s + row * 264 + kc * 8) =
            *reinterpret_cast<const f16x8*>(Vb + row * 256 + kc * 8);
    }
    __syncthreads();

    // ac = a @ corr
    {
        f32x4 acc[4][4] = {};
        for (int ks = 0; ks < 8; ++ks) {
            f16x8 af[4];
            #pragma unroll
            for (int mf = 0; mf < 4; ++mf)
                af[mf] = *reinterpret_cast<const f16x8*>(a_s + (mf * 16 + lm) * 264 + ks * 32 + q * 8);
            #pragma unroll
            for (int nf = 0; nf < 4; ++nf) {
                int e = w * 64 + nf * 16 + lm;
                f16x8 bf = *reinterpret_cast<const f16x8*>(corrT + (size_t)e * 256 + ks * 32 + q * 8);
                #pragma unroll
                for (int mf = 0; mf < 4; ++mf)
                    acc[mf][nf] = __builtin_amdgcn_mfma_f32_16x16x32_f16(af[mf], bf, acc[mf][nf], 0, 0, 0);
            }
        }
        #pragma unroll
        for (int mf = 0; mf < 4; ++mf)
            #pragma unroll
            for (int nf = 0; nf < 4; ++nf)
                #pragma unroll
                for (int r = 0; r < 4; ++r)
                    ac_s[(mf * 16 + 4 * q + r) * 264 + (w * 64 + nf * 16 + lm)] = (_Float16)acc[mf][nf][r];
    }
    __syncthreads();

    // cc = ac @ v^T
    {
        f32x4 acc[4] = {};
        for (int ks = 0; ks < 8; ++ks) {
            f16x8 bf = *reinterpret_cast<const f16x8*>(v_s + (w * 16 + lm) * 264 + ks * 32 + q * 8);
            #pragma unroll
            for (int mf = 0; mf < 4; ++mf) {
                f16x8 af = *reinterpret_cast<const f16x8*>(ac_s + (mf * 16 + lm) * 264 + ks * 32 + q * 8);
                acc[mf] = __builtin_amdgcn_mfma_f32_16x16x32_f16(af, bf, acc[mf], 0, 0, 0);
            }
        }
        #pragma unroll
        for (int mf = 0; mf < 4; ++mf)
            #pragma unroll
            for (int r = 0; r < 4; ++r)
                cc_s[(mf * 16 + 4 * q + r) * 66 + (w * 16 + lm)] = acc[mf][r];
    }
    __syncthreads();

    // dual softmax (+identity)
    {
        int j = t & 63, seg = w;
        float cmx = -1e30f, rmx = -1e30f;
        #pragma unroll
        for (int k = 0; k < 16; ++k) {
            int i = seg * 16 + k;
            cmx = fmaxf(cmx, cc_s[i * 66 + j]);
            rmx = fmaxf(rmx, cc_s[j * 66 + i]);
        }
        red[0 * 256 + seg * 64 + j] = cmx;
        red[2 * 256 + seg * 64 + j] = rmx;
        __syncthreads();
        float cm = fmaxf(fmaxf(red[0 * 256 + 0 * 64 + j], red[0 * 256 + 1 * 64 + j]),
                         fmaxf(red[0 * 256 + 2 * 64 + j], red[0 * 256 + 3 * 64 + j]));
        float rm = fmaxf(fmaxf(red[2 * 256 + 0 * 64 + j], red[2 * 256 + 1 * 64 + j]),
                         fmaxf(red[2 * 256 + 2 * 64 + j], red[2 * 256 + 3 * 64 + j]));
        float cs = 0.f, rs = 0.f;
        #pragma unroll
        for (int k = 0; k < 16; ++k) {
            int i = seg * 16 + k;
            cs += __expf(cc_s[i * 66 + j] - cm);
            rs += __expf(cc_s[j * 66 + i] - rm);
        }
        red[1 * 256 + seg * 64 + j] = cs;
        red[3 * 256 + seg * 64 + j] = rs;
        __syncthreads();
        float csum = red[1 * 256 + 0 * 64 + j] + red[1 * 256 + 1 * 64 + j] +
                     red[1 * 256 + 2 * 64 + j] + red[1 * 256 + 3 * 64 + j];
        float rsum = red[3 * 256 + 0 * 64 + j] + red[3 * 256 + 1 * 64 + j] +
                     red[3 * 256 + 2 * 64 + j] + red[3 * 256 + 3 * 64 + j];
        float cinv = 1.f / csum, rinv = 1.f / rsum;
        #pragma unroll
        for (int k = 0; k < 16; ++k) {
            int i = seg * 16 + k;
            float pa = __expf(cc_s[i * 66 + j] - cm) * cinv;
            if (i == j) pa += 1.f;
            attAT[j * 72 + i] = (_Float16)pa;
            float pv = __expf(cc_s[j * 66 + i] - rm) * rinv;
            if (i == j) pv += 1.f;
            attV[j * 72 + i] = (_Float16)pv;
        }
    }

    // aw = a@Wb_top (waves 0,1), vw = v@Wb_bot (waves 2,3)
    {
        int isV = w >> 1, wcol = w & 1;
        const _Float16* src = isV ? v_s : a_s;
        const int doff = isV ? 256 : 0;
        f32x4 acc[4][2] = {};
        for (int ks = 0; ks < 8; ++ks) {
            f16x8 af[4];
            #pragma unroll
            for (int mf = 0; mf < 4; ++mf)
                af[mf] = *reinterpret_cast<const f16x8*>(src + (mf * 16 + lm) * 264 + ks * 32 + q * 8);
            #pragma unroll
            for (int nf = 0; nf < 2; ++nf) {
                int o = wcol * 32 + nf * 16 + lm;
                f16x8 bf = *reinterpret_cast<const f16x8*>(WbT + (size_t)o * 512 + doff + ks * 32 + q * 8);
                #pragma unroll
                for (int mf = 0; mf < 4; ++mf)
                    acc[mf][nf] = __builtin_amdgcn_mfma_f32_16x16x32_f16(af[mf], bf, acc[mf][nf], 0, 0, 0);
            }
        }
        _Float16* dst = isV ? vwT : awT;
        #pragma unroll
        for (int mf = 0; mf < 4; ++mf)
            #pragma unroll
            for (int nf = 0; nf < 2; ++nf)
                #pragma unroll
                for (int r = 0; r < 4; ++r)
                    dst[(wcol * 32 + nf * 16 + lm) * 72 + (mf * 16 + 4 * q + r)] = (_Float16)acc[mf][nf][r];
    }
    __syncthreads();

    // h = attA^T@aw + attV@vw
    f32x4 hacc[4] = {};
    #pragma unroll
    for (int kk = 0; kk < 2; ++kk) {
        f16x8 a1 = *reinterpret_cast<const f16x8*>(attAT + (16 * w + lm) * 72 + kk * 32 + q * 8);
        f16x8 a2 = *reinterpret_cast<const f16x8*>(attV  + (16 * w + lm) * 72 + kk * 32 + q * 8);
        #pragma unroll
        for (int nf = 0; nf < 4; ++nf) {
            f16x8 b1 = *reinterpret_cast<const f16x8*>(awT + (nf * 16 + lm) * 72 + kk * 32 + q * 8);
            f16x8 b2 = *reinterpret_cast<const f16x8*>(vwT + (nf * 16 + lm) * 72 + kk * 32 + q * 8);
            hacc[nf] = __builtin_amdgcn_mfma_f32_16x16x32_f16(a1, b1, hacc[nf], 0, 0, 0);
            hacc[nf] = __builtin_amdgcn_mfma_f32_16x16x32_f16(a2, b2, hacc[nf], 0, 0, 0);
        }
    }

    // +bb, LayerNorm, ReLU, store
    {
        float bbv[4], gv[4], bev[4];
        #pragma unroll
        for (int nf = 0; nf < 4; ++nf) {
            int o = nf * 16 + lm;
            bbv[nf] = bb[o]; gv[nf] = gamma[o]; bev[nf] = beta[o];
        }
        #pragma unroll
        for (int r = 0; r < 4; ++r) {
            float vals[4]; float s1 = 0.f, s2 = 0.f;
            #pragma unroll
            for (int nf = 0; nf < 4; ++nf) {
                float hv = hacc[nf][r] + bbv[nf];
                vals[nf] = hv; s1 += hv; s2 += hv * hv;
            }
            #pragma unroll
            for (int m = 1; m < 16; m <<= 1) {
                s1 += __shfl_xor(s1, m, 64);
                s2 += __shfl_xor(s2, m, 64);
            }
            float mu = s1 * 0.015625f;
            float var = s2 * 0.015625f - mu * mu;
            float rstd = rsqrtf(var + 1e-5f);
            int s = 16 * w + 4 * q + r;
            float* orow = out + ((size_t)b * 64 + s) * 64;
            #pragma unroll
            for (int nf = 0; nf < 4; ++nf) {
                float y = (vals[nf] - mu) * rstd * gv[nf] + bev[nf];
                orow[nf * 16 + lm] = fmaxf(y, 0.f);
            }
        }
    }
}

// =========================================================
extern "C" void kernel_launch(void* const* d_in, const int* in_sizes, int n_in,
                              void* d_out, int out_size, void* d_ws, size_t ws_size,
                              hipStream_t stream) {
    const float* Xa    = (const float*)d_in[0];
    const float* Xv    = (const float*)d_in[1];
    const float* Wa    = (const float*)d_in[2];
    const float* ba    = (const float*)d_in[3];
    const float* Wv    = (const float*)d_in[4];
    const float* bv    = (const float*)d_in[5];
    const float* corr  = (const float*)d_in[6];
    const float* Wb    = (const float*)d_in[7];
    const float* bb    = (const float*)d_in[8];
    const float* gamma = (const float*)d_in[9];
    const float* beta  = (const float*)d_in[10];
    float* out = (float*)d_out;
    char* ws = (char*)d_ws;

    _Float16* a16   = (_Float16*)(ws + A16_OFF);
    _Float16* v16   = (_Float16*)(ws + V16_OFF);
    _Float16* WaP   = (_Float16*)(ws + WAP_OFF);
    _Float16* WvP   = (_Float16*)(ws + WVP_OFF);
    _Float16* corrT = (_Float16*)(ws + CORRT_OFF);
    _Float16* WbT   = (_Float16*)(ws + WBT_OFF);

    hipLaunchKernelGGL(k_prep, dim3(216), dim3(256), 0, stream,
                       Wa, Wv, corr, Wb, WaP, WvP, corrT, WbT);
    (void)hipFuncSetAttribute((const void*)k_proj,
                              hipFuncAttributeMaxDynamicSharedMemorySize, 98304);
    hipLaunchKernelGGL(k_proj, dim3(256), dim3(512), 98304, stream,
                       Xa, Xv, WaP, WvP, ba, bv, a16, v16);
    (void)hipFuncSetAttribute((const void*)k_fuse,
                              hipFuncAttributeMaxDynamicSharedMemorySize, SM_TOTAL);
    hipLaunchKernelGGL(k_fuse, dim3(512), dim3(256), SM_TOTAL, stream,
                       a16, v16, corrT, WbT, bb, gamma, beta, out);
}